// Round 8
// baseline (340.671 us; speedup 1.0000x reference)
//
#include <hip/hip_runtime.h>
#include <hip/hip_fp16.h>
#include <cstdint>
#include <cstddef>

// ---------------------------------------------------------------------------
// LightGCN on MI355X — atomic-free CSR build + fp16 Y-scaled gather storage.
//   Y-substitution: Y_l = diag(deg^-1/2) X_l  =>  Y_{l+1} = (1/deg) * sum Y_l[c]
//     -> SpMM inner loop is a PURE gather-sum (no per-edge weight load/mul).
//   CSR build: fixed-capacity bucket partition (wave-shuffle scans) ->
//     bucket_scan -> per-bucket finalize (row_ptr, dis, dis2=1/deg,
//     invd=sqrt(deg), dense col-only cv).
//   convert: fp32 tables -> Y0 fp16 (128B rows).
//   Layer 3 fused into batch gather (X_l = Y_l*invd; X0 from fp32 tables).
// ---------------------------------------------------------------------------

typedef __attribute__((ext_vector_type(8))) _Float16 half8;

#define NB_SHIFT 8
#define BCAP 16000      // max edges per 256-row bucket (expected max ~10.7K)
#define P1_TILE 8192
#define P1_DIM 512
#define FIN_CAP 16384

__global__ void bucket_init_kernel(int* __restrict__ bcur, int nb) {
    int b = blockIdx.x * blockDim.x + threadIdx.x;
    if (b < nb) bcur[b] = b * BCAP;
}

// ---- partition into fixed-capacity bucket regions ----
__global__ __launch_bounds__(P1_DIM) void partition_kernel(
    const int* __restrict__ rows, const int* __restrict__ cols,
    int* __restrict__ bucket_cursor, int* __restrict__ tmp,
    int nnz, int nb) {
    __shared__ int            lhist[1024];
    __shared__ int            loff[1024];
    __shared__ int            ldelta[1024];   // lbase[b] - loff[b]
    __shared__ int            wsum[8];
    __shared__ int            stage[P1_TILE]; // packed (r_local<<18)|col
    __shared__ unsigned short bstage[P1_TILE];
    int t = threadIdx.x;
    int lane = t & 63, wv = t >> 6;
    int base     = blockIdx.x * P1_TILE;
    int cnt_here = min(P1_TILE, nnz - base);
    int full4    = cnt_here >> 2;
    int rem      = cnt_here & 3;
    for (int i = t; i < 1024; i += P1_DIM) lhist[i] = 0;
    __syncthreads();
    const int4* rows4 = (const int4*)(rows + base);
    const int4* cols4 = (const int4*)(cols + base);
    int4 rr[4], cc[4];
    int  rk[16];
#pragma unroll
    for (int k = 0; k < 4; ++k) {
        int i4 = t + k * P1_DIM;
        if (i4 < full4) {
            rr[k] = rows4[i4];
            cc[k] = cols4[i4];
            rk[4 * k + 0] = atomicAdd(&lhist[rr[k].x >> NB_SHIFT], 1);
            rk[4 * k + 1] = atomicAdd(&lhist[rr[k].y >> NB_SHIFT], 1);
            rk[4 * k + 2] = atomicAdd(&lhist[rr[k].z >> NB_SHIFT], 1);
            rk[4 * k + 3] = atomicAdd(&lhist[rr[k].w >> NB_SHIFT], 1);
        }
    }
    int re = 0, ce = 0, rke = 0;
    bool has_rem = (t < rem);
    if (has_rem) {
        re  = rows[base + 4 * full4 + t];
        ce  = cols[base + 4 * full4 + t];
        rke = atomicAdd(&lhist[re >> NB_SHIFT], 1);
    }
    __syncthreads();
    // wave-shuffle exclusive scan over 1024 bucket counts (2 per thread)
    int v0 = lhist[2 * t], v1 = lhist[2 * t + 1];
    int ts = v0 + v1;
    int sc = ts;
#pragma unroll
    for (int off = 1; off < 64; off <<= 1) {
        int x = __shfl_up(sc, off);
        if (lane >= off) sc += x;
    }
    if (lane == 63) wsum[wv] = sc;
    __syncthreads();
    int prefix = 0;
#pragma unroll
    for (int k = 0; k < 8; ++k) {
        int s = wsum[k];
        prefix += (k < wv) ? s : 0;
    }
    int run = prefix + sc - ts;  // exclusive prefix of ts
    loff[2 * t]     = run;
    loff[2 * t + 1] = run + v0;
#pragma unroll
    for (int k = 0; k < 2; ++k) {
        int b  = 2 * t + k;
        int vv = (k == 0) ? v0 : v1;
        if (b < nb && vv > 0)
            ldelta[b] = atomicAdd(&bucket_cursor[b], vv) - loff[b];
    }
    __syncthreads();
#pragma unroll
    for (int k = 0; k < 4; ++k) {
        int i4 = t + k * P1_DIM;
        if (i4 < full4) {
            int r4[4] = {rr[k].x, rr[k].y, rr[k].z, rr[k].w};
            int c4[4] = {cc[k].x, cc[k].y, cc[k].z, cc[k].w};
#pragma unroll
            for (int e = 0; e < 4; ++e) {
                int b = r4[e] >> NB_SHIFT;
                int s = loff[b] + rk[4 * k + e];
                stage[s]  = ((r4[e] & 255) << 18) | c4[e];
                bstage[s] = (unsigned short)b;
            }
        }
    }
    if (has_rem) {
        int b = re >> NB_SHIFT;
        int s = loff[b] + rke;
        stage[s]  = ((re & 255) << 18) | ce;
        bstage[s] = (unsigned short)b;
    }
    __syncthreads();
    for (int s = t; s < cnt_here; s += P1_DIM) {
        tmp[s + ldelta[bstage[s]]] = stage[s];
    }
}

// ---- exclusive scan of per-bucket counts (derived from cursors) ----
__global__ __launch_bounds__(256) void bucket_scan_kernel(
    const int* __restrict__ bcur, int* __restrict__ bucket_base,
    int nb, int nnz) {
    __shared__ int sdata[256];
    int t = threadIdx.x;
    int v[3];
#pragma unroll
    for (int k = 0; k < 3; ++k) {
        int i = 3 * t + k;
        v[k] = (i < nb) ? (bcur[i] - i * BCAP) : 0;
    }
    int ts = v[0] + v[1] + v[2];
    sdata[t] = ts;
    __syncthreads();
    for (int off = 1; off < 256; off <<= 1) {
        int x = 0;
        if (t >= off) x = sdata[t - off];
        __syncthreads();
        if (t >= off) sdata[t] += x;
        __syncthreads();
    }
    int run = sdata[t] - ts;
#pragma unroll
    for (int k = 0; k < 3; ++k) {
        int i = 3 * t + k;
        if (i < nb) {
            bucket_base[i] = run;
            run += v[k];
        }
    }
    if (t == 255) bucket_base[nb] = nnz;
}

// ---- per-bucket finalize: row_ptr, dis, dis2, invd, dense coalesced cv ----
__global__ __launch_bounds__(256) void finalize_kernel(
    const int* __restrict__ tmp, const int* __restrict__ bucket_base,
    int* __restrict__ row_ptr, float* __restrict__ dis,
    float* __restrict__ dis2, float* __restrict__ invd,
    int* __restrict__ cv, int n_nodes, int nb, int nnz) {
    __shared__ int rcnt[256];
    __shared__ int ccur[256];
    __shared__ int wsum[4];
    __shared__ int stage[FIN_CAP];
    int b = blockIdx.x;
    int t = threadIdx.x;
    int lane = t & 63, wv = t >> 6;
    int src   = b * BCAP;
    int dbeg  = bucket_base[b];
    int count = bucket_base[b + 1] - dbeg;
    rcnt[t] = 0;
    __syncthreads();
    for (int i = t; i < count; i += 256) {
        atomicAdd(&rcnt[tmp[src + i] >> 18], 1);
    }
    __syncthreads();
    int v = rcnt[t];
    int sc = v;
#pragma unroll
    for (int off = 1; off < 64; off <<= 1) {
        int x = __shfl_up(sc, off);
        if (lane >= off) sc += x;
    }
    if (lane == 63) wsum[wv] = sc;
    __syncthreads();
    int prefix = 0;
#pragma unroll
    for (int k = 0; k < 4; ++k) {
        int s = wsum[k];
        prefix += (k < wv) ? s : 0;
    }
    int ex = prefix + sc - v;
    ccur[t] = ex;
    int row = (b << NB_SHIFT) + t;
    if (row < n_nodes) {
        row_ptr[row] = dbeg + ex;
        double dv = (double)v;
        dis[row]  = (v > 0) ? (float)(1.0 / sqrt(dv)) : 0.0f;
        dis2[row] = (v > 0) ? (float)(1.0 / dv) : 0.0f;
        invd[row] = (v > 0) ? (float)sqrt(dv) : 0.0f;
    }
    if (b == nb - 1 && t == 0) row_ptr[n_nodes] = nnz;
    __syncthreads();
    for (int i = t; i < count; i += 256) {
        int p  = tmp[src + i];
        int rk = atomicAdd(&ccur[p >> 18], 1);
        stage[rk] = p & 0x3FFFF;
    }
    __syncthreads();
    for (int s = t; s < count; s += 256) {
        cv[dbeg + s] = stage[s];
    }
}

// ---- fp32 tables -> Y0 = dis * X0 (fp16, 128B rows) ----
__global__ __launch_bounds__(256) void convert_kernel(
    const float4* __restrict__ ut4, const float4* __restrict__ it4,
    const float* __restrict__ dis, half8* __restrict__ Yh,
    int usernum, int n_nodes) {
    int total = n_nodes * 8;   // 8 chunks of 8 dims per row
    for (int i = blockIdx.x * blockDim.x + threadIdx.x; i < total;
         i += gridDim.x * blockDim.x) {
        int row = i >> 3;
        int c   = i & 7;
        float d = dis[row];
        const float4* src = (row <= usernum)
            ? (ut4 + (size_t)row * 16 + 2 * c)
            : (it4 + (size_t)(row - usernum) * 16 + 2 * c);
        float4 a = src[0];
        float4 b = src[1];
        half8 o;
        o[0] = (_Float16)(d * a.x); o[1] = (_Float16)(d * a.y);
        o[2] = (_Float16)(d * a.z); o[3] = (_Float16)(d * a.w);
        o[4] = (_Float16)(d * b.x); o[5] = (_Float16)(d * b.y);
        o[6] = (_Float16)(d * b.z); o[7] = (_Float16)(d * b.w);
        Yh[i] = o;
    }
}

// ---- pure gather-sum CSR row: 8 edge-slots x 8 lanes x half8 ----
__device__ inline void csr_row_sum_h(const _Float16* __restrict__ Yh,
                                     const int* __restrict__ cv,
                                     int beg, int end, int g, int l8,
                                     float* acc /*[8]*/) {
    int j = beg + g;
    for (; j + 8 < end; j += 16) {
        int c0 = cv[j], c1 = cv[j + 8];
        half8 x0 = ((const half8*)(Yh + (size_t)c0 * 64))[l8];
        half8 x1 = ((const half8*)(Yh + (size_t)c1 * 64))[l8];
#pragma unroll
        for (int k = 0; k < 8; ++k) {
            acc[k] += (float)x0[k] + (float)x1[k];
        }
    }
    if (j < end) {
        int c0 = cv[j];
        half8 x0 = ((const half8*)(Yh + (size_t)c0 * 64))[l8];
#pragma unroll
        for (int k = 0; k < 8; ++k) {
            acc[k] += (float)x0[k];
        }
    }
#pragma unroll
    for (int off = 8; off <= 32; off <<= 1) {
#pragma unroll
        for (int k = 0; k < 8; ++k) acc[k] += __shfl_xor(acc[k], off);
    }
}

// Y_{l+1}[r] = (1/deg[r]) * sum_e Y_l[c]
__global__ __launch_bounds__(256) void spmm_y_kernel(
    const _Float16* __restrict__ Yin, _Float16* __restrict__ Yout,
    const int* __restrict__ row_ptr, const int* __restrict__ cv,
    const float* __restrict__ dis2, int n_nodes) {
    int wid  = (blockIdx.x * blockDim.x + threadIdx.x) >> 6;
    int lane = threadIdx.x & 63;
    if (wid >= n_nodes) return;
    int beg = row_ptr[wid];
    int end = row_ptr[wid + 1];
    float d2 = dis2[wid];
    int g = lane >> 3, l8 = lane & 7;
    float acc[8] = {0.f, 0.f, 0.f, 0.f, 0.f, 0.f, 0.f, 0.f};
    csr_row_sum_h(Yin, cv, beg, end, g, l8, acc);
    if (g == 0) {
        half8 o;
#pragma unroll
        for (int k = 0; k < 8; ++k) o[k] = (_Float16)(acc[k] * d2);
        ((half8*)(Yout + (size_t)wid * 64))[l8] = o;
    }
}

// fused layer-3 + gather:
// accb[w] = X0fp32[idx] + invd*(Y1[idx]+Y2[idx]) + dis[idx]*sum_e Y2[c]
__global__ __launch_bounds__(256) void final_gather_kernel(
    const float* __restrict__ ut, const float* __restrict__ itb,
    const _Float16* __restrict__ Y1, const _Float16* __restrict__ Y2,
    const int* __restrict__ row_ptr, const int* __restrict__ cv,
    const float* __restrict__ dis, const float* __restrict__ invd,
    const int* __restrict__ user_ids, const int* __restrict__ pos_seqs,
    const int* __restrict__ neg_seqs, float* __restrict__ accb,
    int usernum, int itemnum, int batch) {
    int w    = (blockIdx.x * blockDim.x + threadIdx.x) >> 6;
    int lane = threadIdx.x & 63;
    if (w >= 3 * batch) return;
    int which = w / batch;
    int b     = w - which * batch;
    int idx;
    const float* base0;
    if (which == 0) {
        int u = min(max(user_ids[b], 0), usernum);
        idx = u;
        base0 = ut + (size_t)u * 64;
    } else {
        const int* seq = (which == 1) ? pos_seqs : neg_seqs;
        int p = min(max(seq[b], 1), itemnum);
        idx = usernum + p;
        base0 = itb + (size_t)p * 64;
    }
    int beg = row_ptr[idx];
    int end = row_ptr[idx + 1];
    float dr = dis[idx];
    float iv = invd[idx];
    int g = lane >> 3, l8 = lane & 7;
    float acc[8] = {0.f, 0.f, 0.f, 0.f, 0.f, 0.f, 0.f, 0.f};
    csr_row_sum_h(Y2, cv, beg, end, g, l8, acc);
    if (g == 0) {
        const float4* p0 = (const float4*)base0 + 2 * l8;
        float4 a = p0[0], c = p0[1];
        half8 y1 = ((const half8*)(Y1 + (size_t)idx * 64))[l8];
        half8 y2 = ((const half8*)(Y2 + (size_t)idx * 64))[l8];
        float o[8];
        o[0] = a.x; o[1] = a.y; o[2] = a.z; o[3] = a.w;
        o[4] = c.x; o[5] = c.y; o[6] = c.z; o[7] = c.w;
#pragma unroll
        for (int k = 0; k < 8; ++k) {
            o[k] += iv * ((float)y1[k] + (float)y2[k]) + acc[k] * dr;
        }
        float4* dst = (float4*)(accb + (size_t)w * 64) + 2 * l8;
        float4 d0, d1;
        d0.x = o[0]; d0.y = o[1]; d0.z = o[2]; d0.w = o[3];
        d1.x = o[4]; d1.y = o[5]; d1.z = o[6]; d1.w = o[7];
        dst[0] = d0; dst[1] = d1;
    }
}

__global__ void logits_kernel(const float* __restrict__ acc,
                              float* __restrict__ out, int batch) {
    int w    = (blockIdx.x * blockDim.x + threadIdx.x) >> 6;
    int lane = threadIdx.x & 63;
    if (w >= batch) return;
    float u = acc[(size_t)w * 64 + lane];
    float p = acc[(size_t)(batch + w) * 64 + lane];
    float n = acc[(size_t)(2 * batch + w) * 64 + lane];
    float dp = u * p;
    float dn = u * n;
#pragma unroll
    for (int off = 32; off > 0; off >>= 1) {
        dp += __shfl_xor(dp, off, 64);
        dn += __shfl_xor(dn, off, 64);
    }
    if (lane == 0) {
        out[w]         = dp * 0.0625f;
        out[batch + w] = dn * 0.0625f;
    }
}

extern "C" void kernel_launch(void* const* d_in, const int* in_sizes, int n_in,
                              void* d_out, int out_size, void* d_ws,
                              size_t ws_size, hipStream_t stream) {
    const float* user_table = (const float*)d_in[0];
    const float* item_table = (const float*)d_in[1];
    const int*   rows       = (const int*)d_in[3];
    const int*   cols       = (const int*)d_in[4];
    const int*   user_ids   = (const int*)d_in[5];
    const int*   pos_seqs   = (const int*)d_in[6];
    const int*   neg_seqs   = (const int*)d_in[7];
    float*       out        = (float*)d_out;

    const int D = 64;
    int usernum = in_sizes[0] / D - 1;   // 100000
    int itemnum = in_sizes[1] / D - 1;   // 50000
    int nnz     = in_sizes[2];           // 4,000,000
    int batch   = in_sizes[5];           // 4096
    int n_nodes = usernum + itemnum + 1; // 150001
    int nb      = (n_nodes + (1 << NB_SHIFT) - 1) >> NB_SHIFT;  // 586

    // ---- workspace layout ----
    char* w = (char*)d_ws;
    auto alloc = [&](size_t bytes) {
        char* p = w;
        w += (bytes + 255) & ~(size_t)255;
        return p;
    };
    _Float16* Yh0   = (_Float16*)alloc((size_t)n_nodes * D * 2);  // 19.2 MB
    _Float16* Yh1   = (_Float16*)alloc((size_t)n_nodes * D * 2);  // 19.2 MB
    _Float16* Yh2   = (_Float16*)alloc((size_t)n_nodes * D * 2);  // 19.2 MB
    int*   cv       = (int*)alloc((size_t)nnz * 4);               // 16 MB
    int*   row_ptr  = (int*)alloc((size_t)(n_nodes + 1) * 4);
    float* dis      = (float*)alloc((size_t)n_nodes * 4);
    float* dis2     = (float*)alloc((size_t)n_nodes * 4);
    float* invd     = (float*)alloc((size_t)n_nodes * 4);
    int*   bbase    = (int*)alloc(4096);
    int*   bcur     = (int*)alloc(4096);
    float* accb     = (float*)alloc((size_t)3 * batch * D * 4);   // 3 MB
    // partition scratch: 586*16000*4 = 37.5 MB, aliases Yh1+Yh2 (38.4 MB);
    // dead after finalize; Yh1/Yh2 written only afterwards.
    int*   tmp      = (int*)Yh1;

    // ---- CSR build ----
    bucket_init_kernel<<<3, 256, 0, stream>>>(bcur, nb);
    int p1_tiles = (nnz + P1_TILE - 1) / P1_TILE;
    partition_kernel<<<p1_tiles, P1_DIM, 0, stream>>>(rows, cols, bcur, tmp,
                                                      nnz, nb);
    bucket_scan_kernel<<<1, 256, 0, stream>>>(bcur, bbase, nb, nnz);
    finalize_kernel<<<nb, 256, 0, stream>>>(tmp, bbase, row_ptr, dis, dis2,
                                            invd, cv, n_nodes, nb, nnz);

    // ---- Y0 = dis * X0 in fp16 ----
    convert_kernel<<<(n_nodes * 8 + 255) / 256, 256, 0, stream>>>(
        (const float4*)user_table, (const float4*)item_table, dis,
        (half8*)Yh0, usernum, n_nodes);

    // ---- layers: Yh0 -> Yh1 -> Yh2 (pure gather-sum + 1/deg scale) ----
    int spmm_grid = (n_nodes + 3) / 4;
    spmm_y_kernel<<<spmm_grid, 256, 0, stream>>>(Yh0, Yh1, row_ptr, cv, dis2,
                                                 n_nodes);
    spmm_y_kernel<<<spmm_grid, 256, 0, stream>>>(Yh1, Yh2, row_ptr, cv, dis2,
                                                 n_nodes);

    // ---- fused layer-3 + gather ----
    int gather_grid = (3 * batch + 3) / 4;
    final_gather_kernel<<<gather_grid, 256, 0, stream>>>(
        user_table, item_table, Yh1, Yh2, row_ptr, cv, dis, invd, user_ids,
        pos_seqs, neg_seqs, accb, usernum, itemnum, batch);

    // ---- final logits ----
    logits_kernel<<<(batch + 3) / 4, 256, 0, stream>>>(accb, out, batch);
}

// Round 9
// 326.025 us; speedup vs baseline: 1.0449x; 1.0449x over previous
//
#include <hip/hip_runtime.h>
#include <hip/hip_fp16.h>
#include <cstdint>
#include <cstddef>

// ---------------------------------------------------------------------------
// LightGCN on MI355X — atomic-free CSR build + fp16 Y-scaled gather storage.
//   Y-substitution: Y_l = diag(deg^-1/2) X_l => Y_{l+1} = (1/deg)*sum Y_l[c]
//     -> SpMM inner loop is a pure gather-sum. Pairwise fp16 pre-add
//     (v_pk_add_f16) + runtime-1.0 mad_mix accumulate; 32-bit saddr offsets.
//   CSR build: bucket partition (cursor deltas, memset-init) -> bucket_scan
//     -> finalize (2-pass, no LDS stage: direct L2-merged cv writes).
//   convert: fp32 tables -> Y0 fp16 (128B rows).
//   Layer 3 fused into batch gather (X_l = Y_l*invd; X0 from fp32 tables).
// ---------------------------------------------------------------------------

typedef __attribute__((ext_vector_type(8))) _Float16 half8;

#define NB_SHIFT 8
#define BCAP 16000      // max edges per 256-row bucket (expected max ~10.7K)
#define P1_TILE 8192
#define P1_DIM 512

// ---- partition into fixed-capacity bucket regions (bcur = per-bucket delta) ----
__global__ __launch_bounds__(P1_DIM) void partition_kernel(
    const int* __restrict__ rows, const int* __restrict__ cols,
    int* __restrict__ bucket_cursor, int* __restrict__ tmp,
    int nnz, int nb) {
    __shared__ int            lhist[1024];
    __shared__ int            loff[1024];
    __shared__ int            ldelta[1024];   // dest_base[b] - loff[b]
    __shared__ int            wsum[8];
    __shared__ int            stage[P1_TILE]; // packed (r_local<<18)|col
    __shared__ unsigned short bstage[P1_TILE];
    int t = threadIdx.x;
    int lane = t & 63, wv = t >> 6;
    int base     = blockIdx.x * P1_TILE;
    int cnt_here = min(P1_TILE, nnz - base);
    int full4    = cnt_here >> 2;
    int rem      = cnt_here & 3;
    for (int i = t; i < 1024; i += P1_DIM) lhist[i] = 0;
    __syncthreads();
    const int4* rows4 = (const int4*)(rows + base);
    const int4* cols4 = (const int4*)(cols + base);
    int4 rr[4], cc[4];
    int  rk[16];
#pragma unroll
    for (int k = 0; k < 4; ++k) {
        int i4 = t + k * P1_DIM;
        if (i4 < full4) {
            rr[k] = rows4[i4];
            cc[k] = cols4[i4];
            rk[4 * k + 0] = atomicAdd(&lhist[rr[k].x >> NB_SHIFT], 1);
            rk[4 * k + 1] = atomicAdd(&lhist[rr[k].y >> NB_SHIFT], 1);
            rk[4 * k + 2] = atomicAdd(&lhist[rr[k].z >> NB_SHIFT], 1);
            rk[4 * k + 3] = atomicAdd(&lhist[rr[k].w >> NB_SHIFT], 1);
        }
    }
    int re = 0, ce = 0, rke = 0;
    bool has_rem = (t < rem);
    if (has_rem) {
        re  = rows[base + 4 * full4 + t];
        ce  = cols[base + 4 * full4 + t];
        rke = atomicAdd(&lhist[re >> NB_SHIFT], 1);
    }
    __syncthreads();
    // wave-shuffle exclusive scan over 1024 bucket counts (2 per thread)
    int v0 = lhist[2 * t], v1 = lhist[2 * t + 1];
    int ts = v0 + v1;
    int sc = ts;
#pragma unroll
    for (int off = 1; off < 64; off <<= 1) {
        int x = __shfl_up(sc, off);
        if (lane >= off) sc += x;
    }
    if (lane == 63) wsum[wv] = sc;
    __syncthreads();
    int prefix = 0;
#pragma unroll
    for (int k = 0; k < 8; ++k) {
        int s = wsum[k];
        prefix += (k < wv) ? s : 0;
    }
    int run = prefix + sc - ts;  // exclusive prefix of ts
    loff[2 * t]     = run;
    loff[2 * t + 1] = run + v0;
#pragma unroll
    for (int k = 0; k < 2; ++k) {
        int b  = 2 * t + k;
        int vv = (k == 0) ? v0 : v1;
        if (b < nb && vv > 0) {
            int old = atomicAdd(&bucket_cursor[b], vv);   // delta in bucket
            ldelta[b] = b * BCAP + old - loff[b];
        }
    }
    __syncthreads();
#pragma unroll
    for (int k = 0; k < 4; ++k) {
        int i4 = t + k * P1_DIM;
        if (i4 < full4) {
            int r4[4] = {rr[k].x, rr[k].y, rr[k].z, rr[k].w};
            int c4[4] = {cc[k].x, cc[k].y, cc[k].z, cc[k].w};
#pragma unroll
            for (int e = 0; e < 4; ++e) {
                int b = r4[e] >> NB_SHIFT;
                int s = loff[b] + rk[4 * k + e];
                stage[s]  = ((r4[e] & 255) << 18) | c4[e];
                bstage[s] = (unsigned short)b;
            }
        }
    }
    if (has_rem) {
        int b = re >> NB_SHIFT;
        int s = loff[b] + rke;
        stage[s]  = ((re & 255) << 18) | ce;
        bstage[s] = (unsigned short)b;
    }
    __syncthreads();
    for (int s = t; s < cnt_here; s += P1_DIM) {
        tmp[s + ldelta[bstage[s]]] = stage[s];
    }
}

// ---- exclusive scan of per-bucket counts ----
__global__ __launch_bounds__(256) void bucket_scan_kernel(
    const int* __restrict__ bcur, int* __restrict__ bucket_base,
    int nb, int nnz) {
    __shared__ int sdata[256];
    int t = threadIdx.x;
    int v[3];
#pragma unroll
    for (int k = 0; k < 3; ++k) {
        int i = 3 * t + k;
        v[k] = (i < nb) ? bcur[i] : 0;
    }
    int ts = v[0] + v[1] + v[2];
    sdata[t] = ts;
    __syncthreads();
    for (int off = 1; off < 256; off <<= 1) {
        int x = 0;
        if (t >= off) x = sdata[t - off];
        __syncthreads();
        if (t >= off) sdata[t] += x;
        __syncthreads();
    }
    int run = sdata[t] - ts;
#pragma unroll
    for (int k = 0; k < 3; ++k) {
        int i = 3 * t + k;
        if (i < nb) {
            bucket_base[i] = run;
            run += v[k];
        }
    }
    if (t == 255) bucket_base[nb] = nnz;
}

// ---- per-bucket finalize: row_ptr, dis, dis2, invd, direct cv writes ----
__global__ __launch_bounds__(256) void finalize_kernel(
    const int* __restrict__ tmp, const int* __restrict__ bucket_base,
    int* __restrict__ row_ptr, float* __restrict__ dis,
    float* __restrict__ dis2, float* __restrict__ invd,
    int* __restrict__ cv, int n_nodes, int nb, int nnz) {
    __shared__ int rcnt[256];
    __shared__ int ccur[256];
    __shared__ int wsum[4];
    int b = blockIdx.x;
    int t = threadIdx.x;
    int lane = t & 63, wv = t >> 6;
    int src   = b * BCAP;
    int dbeg  = bucket_base[b];
    int count = bucket_base[b + 1] - dbeg;
    rcnt[t] = 0;
    __syncthreads();
    for (int i = t; i < count; i += 256) {
        atomicAdd(&rcnt[tmp[src + i] >> 18], 1);
    }
    __syncthreads();
    int v = rcnt[t];
    int sc = v;
#pragma unroll
    for (int off = 1; off < 64; off <<= 1) {
        int x = __shfl_up(sc, off);
        if (lane >= off) sc += x;
    }
    if (lane == 63) wsum[wv] = sc;
    __syncthreads();
    int prefix = 0;
#pragma unroll
    for (int k = 0; k < 4; ++k) {
        int s = wsum[k];
        prefix += (k < wv) ? s : 0;
    }
    int ex = prefix + sc - v;
    ccur[t] = ex;
    int row = (b << NB_SHIFT) + t;
    if (row < n_nodes) {
        row_ptr[row] = dbeg + ex;
        double dv = (double)v;
        dis[row]  = (v > 0) ? (float)(1.0 / sqrt(dv)) : 0.0f;
        dis2[row] = (v > 0) ? (float)(1.0 / dv) : 0.0f;
        invd[row] = (v > 0) ? (float)sqrt(dv) : 0.0f;
    }
    if (b == nb - 1 && t == 0) row_ptr[n_nodes] = nnz;
    __syncthreads();
    // rank + direct write: dest window ~28KB -> L2 write-merge
    for (int i = t; i < count; i += 256) {
        int p  = tmp[src + i];
        int rk = atomicAdd(&ccur[p >> 18], 1);
        cv[dbeg + rk] = p & 0x3FFFF;
    }
}

// ---- fp32 tables -> Y0 = dis * X0 (fp16, 128B rows) ----
__global__ __launch_bounds__(256) void convert_kernel(
    const float4* __restrict__ ut4, const float4* __restrict__ it4,
    const float* __restrict__ dis, half8* __restrict__ Yh,
    int usernum, int n_nodes) {
    int total = n_nodes * 8;   // 8 chunks of 8 dims per row
    for (int i = blockIdx.x * blockDim.x + threadIdx.x; i < total;
         i += gridDim.x * blockDim.x) {
        int row = i >> 3;
        int c   = i & 7;
        float d = dis[row];
        const float4* src = (row <= usernum)
            ? (ut4 + (size_t)row * 16 + 2 * c)
            : (it4 + (size_t)(row - usernum) * 16 + 2 * c);
        float4 a = src[0];
        float4 b = src[1];
        half8 o;
        o[0] = (_Float16)(d * a.x); o[1] = (_Float16)(d * a.y);
        o[2] = (_Float16)(d * a.z); o[3] = (_Float16)(d * a.w);
        o[4] = (_Float16)(d * b.x); o[5] = (_Float16)(d * b.y);
        o[6] = (_Float16)(d * b.z); o[7] = (_Float16)(d * b.w);
        Yh[i] = o;
    }
}

// ---- pure gather-sum CSR row: 8 edge-slots x 8 lanes x half8 ----
// fp16 pairwise pre-add (v_pk_add_f16) + mad_mix accumulate (one==1.0f).
__device__ inline void csr_row_sum_h(const _Float16* __restrict__ Yh,
                                     const int* __restrict__ cv,
                                     int beg, int end, int g, int l8,
                                     float one, float* acc /*[8]*/) {
    const char* Yb = (const char*)Yh;
    const char* cb = (const char*)cv;
    unsigned lo = (unsigned)l8 * 16u;
    int j = beg + g;
    for (; j + 8 < end; j += 16) {
        unsigned c0 = (unsigned)*(const int*)(cb + ((unsigned)j << 2));
        unsigned c1 = (unsigned)*(const int*)(cb + ((unsigned)(j + 8) << 2));
        half8 x0 = *(const half8*)(Yb + (c0 << 7) + lo);
        half8 x1 = *(const half8*)(Yb + (c1 << 7) + lo);
        half8 tt = x0 + x1;   // 4x v_pk_add_f16
#pragma unroll
        for (int k = 0; k < 8; ++k) {
            acc[k] += one * (float)tt[k];   // v_mad_mix_f32
        }
    }
    if (j < end) {
        unsigned c0 = (unsigned)*(const int*)(cb + ((unsigned)j << 2));
        half8 x0 = *(const half8*)(Yb + (c0 << 7) + lo);
#pragma unroll
        for (int k = 0; k < 8; ++k) {
            acc[k] += one * (float)x0[k];
        }
    }
#pragma unroll
    for (int off = 8; off <= 32; off <<= 1) {
#pragma unroll
        for (int k = 0; k < 8; ++k) acc[k] += __shfl_xor(acc[k], off);
    }
}

// Y_{l+1}[r] = (1/deg[r]) * sum_e Y_l[c]
__global__ __launch_bounds__(256) void spmm_y_kernel(
    const _Float16* __restrict__ Yin, _Float16* __restrict__ Yout,
    const int* __restrict__ row_ptr, const int* __restrict__ cv,
    const float* __restrict__ dis2, float one, int n_nodes) {
    int wid  = (blockIdx.x * blockDim.x + threadIdx.x) >> 6;
    int lane = threadIdx.x & 63;
    if (wid >= n_nodes) return;
    int beg = row_ptr[wid];
    int end = row_ptr[wid + 1];
    float d2 = dis2[wid];
    int g = lane >> 3, l8 = lane & 7;
    float acc[8] = {0.f, 0.f, 0.f, 0.f, 0.f, 0.f, 0.f, 0.f};
    csr_row_sum_h(Yin, cv, beg, end, g, l8, one, acc);
    if (g == 0) {
        half8 o;
#pragma unroll
        for (int k = 0; k < 8; ++k) o[k] = (_Float16)(acc[k] * d2);
        ((half8*)(Yout + (size_t)wid * 64))[l8] = o;
    }
}

// fused layer-3 + gather:
// accb[w] = X0fp32[idx] + invd*(Y1[idx]+Y2[idx]) + dis[idx]*sum_e Y2[c]
__global__ __launch_bounds__(256) void final_gather_kernel(
    const float* __restrict__ ut, const float* __restrict__ itb,
    const _Float16* __restrict__ Y1, const _Float16* __restrict__ Y2,
    const int* __restrict__ row_ptr, const int* __restrict__ cv,
    const float* __restrict__ dis, const float* __restrict__ invd,
    const int* __restrict__ user_ids, const int* __restrict__ pos_seqs,
    const int* __restrict__ neg_seqs, float* __restrict__ accb,
    float one, int usernum, int itemnum, int batch) {
    int w    = (blockIdx.x * blockDim.x + threadIdx.x) >> 6;
    int lane = threadIdx.x & 63;
    if (w >= 3 * batch) return;
    int which = w / batch;
    int b     = w - which * batch;
    int idx;
    const float* base0;
    if (which == 0) {
        int u = min(max(user_ids[b], 0), usernum);
        idx = u;
        base0 = ut + (size_t)u * 64;
    } else {
        const int* seq = (which == 1) ? pos_seqs : neg_seqs;
        int p = min(max(seq[b], 1), itemnum);
        idx = usernum + p;
        base0 = itb + (size_t)p * 64;
    }
    int beg = row_ptr[idx];
    int end = row_ptr[idx + 1];
    float dr = dis[idx];
    float iv = invd[idx];
    int g = lane >> 3, l8 = lane & 7;
    float acc[8] = {0.f, 0.f, 0.f, 0.f, 0.f, 0.f, 0.f, 0.f};
    csr_row_sum_h(Y2, cv, beg, end, g, l8, one, acc);
    if (g == 0) {
        const float4* p0 = (const float4*)base0 + 2 * l8;
        float4 a = p0[0], c = p0[1];
        half8 y1 = ((const half8*)(Y1 + (size_t)idx * 64))[l8];
        half8 y2 = ((const half8*)(Y2 + (size_t)idx * 64))[l8];
        float o[8];
        o[0] = a.x; o[1] = a.y; o[2] = a.z; o[3] = a.w;
        o[4] = c.x; o[5] = c.y; o[6] = c.z; o[7] = c.w;
#pragma unroll
        for (int k = 0; k < 8; ++k) {
            o[k] += iv * ((float)y1[k] + (float)y2[k]) + acc[k] * dr;
        }
        float4* dst = (float4*)(accb + (size_t)w * 64) + 2 * l8;
        float4 d0, d1;
        d0.x = o[0]; d0.y = o[1]; d0.z = o[2]; d0.w = o[3];
        d1.x = o[4]; d1.y = o[5]; d1.z = o[6]; d1.w = o[7];
        dst[0] = d0; dst[1] = d1;
    }
}

__global__ void logits_kernel(const float* __restrict__ acc,
                              float* __restrict__ out, int batch) {
    int w    = (blockIdx.x * blockDim.x + threadIdx.x) >> 6;
    int lane = threadIdx.x & 63;
    if (w >= batch) return;
    float u = acc[(size_t)w * 64 + lane];
    float p = acc[(size_t)(batch + w) * 64 + lane];
    float n = acc[(size_t)(2 * batch + w) * 64 + lane];
    float dp = u * p;
    float dn = u * n;
#pragma unroll
    for (int off = 32; off > 0; off >>= 1) {
        dp += __shfl_xor(dp, off, 64);
        dn += __shfl_xor(dn, off, 64);
    }
    if (lane == 0) {
        out[w]         = dp * 0.0625f;
        out[batch + w] = dn * 0.0625f;
    }
}

extern "C" void kernel_launch(void* const* d_in, const int* in_sizes, int n_in,
                              void* d_out, int out_size, void* d_ws,
                              size_t ws_size, hipStream_t stream) {
    const float* user_table = (const float*)d_in[0];
    const float* item_table = (const float*)d_in[1];
    const int*   rows       = (const int*)d_in[3];
    const int*   cols       = (const int*)d_in[4];
    const int*   user_ids   = (const int*)d_in[5];
    const int*   pos_seqs   = (const int*)d_in[6];
    const int*   neg_seqs   = (const int*)d_in[7];
    float*       out        = (float*)d_out;

    const int D = 64;
    int usernum = in_sizes[0] / D - 1;   // 100000
    int itemnum = in_sizes[1] / D - 1;   // 50000
    int nnz     = in_sizes[2];           // 4,000,000
    int batch   = in_sizes[5];           // 4096
    int n_nodes = usernum + itemnum + 1; // 150001
    int nb      = (n_nodes + (1 << NB_SHIFT) - 1) >> NB_SHIFT;  // 586

    // ---- workspace layout ----
    char* w = (char*)d_ws;
    auto alloc = [&](size_t bytes) {
        char* p = w;
        w += (bytes + 255) & ~(size_t)255;
        return p;
    };
    _Float16* Yh0   = (_Float16*)alloc((size_t)n_nodes * D * 2);  // 19.2 MB
    _Float16* Yh1   = (_Float16*)alloc((size_t)n_nodes * D * 2);  // 19.2 MB
    _Float16* Yh2   = (_Float16*)alloc((size_t)n_nodes * D * 2);  // 19.2 MB
    int*   cv       = (int*)alloc((size_t)nnz * 4);               // 16 MB
    int*   row_ptr  = (int*)alloc((size_t)(n_nodes + 1) * 4);
    float* dis      = (float*)alloc((size_t)n_nodes * 4);
    float* dis2     = (float*)alloc((size_t)n_nodes * 4);
    float* invd     = (float*)alloc((size_t)n_nodes * 4);
    int*   bbase    = (int*)alloc(4096);
    int*   bcur     = (int*)alloc(4096);
    float* accb     = (float*)alloc((size_t)3 * batch * D * 4);   // 3 MB
    // partition scratch: 586*16000*4 = 37.5 MB, aliases Yh1+Yh2 (38.4 MB);
    // dead after finalize; Yh1/Yh2 written only afterwards.
    int*   tmp      = (int*)Yh1;

    // ---- CSR build ----
    hipMemsetAsync(bcur, 0, 4096, stream);
    int p1_tiles = (nnz + P1_TILE - 1) / P1_TILE;
    partition_kernel<<<p1_tiles, P1_DIM, 0, stream>>>(rows, cols, bcur, tmp,
                                                      nnz, nb);
    bucket_scan_kernel<<<1, 256, 0, stream>>>(bcur, bbase, nb, nnz);
    finalize_kernel<<<nb, 256, 0, stream>>>(tmp, bbase, row_ptr, dis, dis2,
                                            invd, cv, n_nodes, nb, nnz);

    // ---- Y0 = dis * X0 in fp16 ----
    convert_kernel<<<(n_nodes * 8 + 255) / 256, 256, 0, stream>>>(
        (const float4*)user_table, (const float4*)item_table, dis,
        (half8*)Yh0, usernum, n_nodes);

    // ---- layers: Yh0 -> Yh1 -> Yh2 (pure gather-sum + 1/deg scale) ----
    const float one = 1.0f;
    int spmm_grid = (n_nodes + 3) / 4;
    spmm_y_kernel<<<spmm_grid, 256, 0, stream>>>(Yh0, Yh1, row_ptr, cv, dis2,
                                                 one, n_nodes);
    spmm_y_kernel<<<spmm_grid, 256, 0, stream>>>(Yh1, Yh2, row_ptr, cv, dis2,
                                                 one, n_nodes);

    // ---- fused layer-3 + gather ----
    int gather_grid = (3 * batch + 3) / 4;
    final_gather_kernel<<<gather_grid, 256, 0, stream>>>(
        user_table, item_table, Yh1, Yh2, row_ptr, cv, dis, invd, user_ids,
        pos_seqs, neg_seqs, accb, one, usernum, itemnum, batch);

    // ---- final logits ----
    logits_kernel<<<(batch + 3) / 4, 256, 0, stream>>>(accb, out, batch);
}